// Round 16
// baseline (451.400 us; speedup 1.0000x reference)
//
#include <hip/hip_runtime.h>
#include <stdint.h>

// Problem constants: B=256, T=128, D=256, H=8, AE=32, DFF=512
#define DEVI static __device__ __forceinline__

typedef __attribute__((ext_vector_type(4))) float f32x4;
typedef __attribute__((ext_vector_type(8))) short bf8;     // 8 bf16 (MFMA A/B frag)
typedef __attribute__((ext_vector_type(4))) unsigned short u16x4;
typedef __attribute__((ext_vector_type(4))) unsigned int u32x4;

DEVI unsigned short f2bf(float f) {
  unsigned u = __builtin_bit_cast(unsigned, f);
  u = (u + 0x7FFFu + ((u >> 16) & 1u)) >> 16;
  return (unsigned short)u;
}
DEVI float bf2f(unsigned short s) {
  return __builtin_bit_cast(float, ((unsigned)s) << 16);
}
DEVI unsigned cvt_pk_bf16(float lo, float hi) {
  unsigned r;
  asm("v_cvt_pk_bf16_f32 %0, %1, %2" : "=v"(r) : "v"(lo), "v"(hi));
  return r;
}
// swizzle for 256-B rows (attn ps): 16B granularity, 8 slots
DEVI int swz(int row) { return (((row >> 2) ^ row) & 7) << 4; }
// swizzle for 64-B rows (gemm As/Ws, attn vs): 16B granularity, 4 slots
DEVI int swz32(int row) { return (((row >> 1) ^ row) & 3) << 4; }

DEVI void gload16(const void* g, void* l) {
  __builtin_amdgcn_global_load_lds(
      (const __attribute__((address_space(1))) unsigned*)g,
      (__attribute__((address_space(3))) unsigned*)l, 16, 0, 0);
}

// ---------------------------------------------------------------------------
// Per-t batched GEMM: C[b-rows, t, n0+*] = sum_k A * Wsel
// Round 14 structure (2-deep W reg prefetch, x2-unrolled K-loop, named regs).
// MI=2: BM=256; MI=1: BM=128 with mx m-blocks. 1-D grid, XCD same-t grouping
// + two-weight fusion. 8 waves, BN=128, BK=32. nt even at all call sites.
// [= round-15 PASS; SILU mode no longer instantiated here]
// ---------------------------------------------------------------------------
template<bool OUT_BF16, int MI>
__global__ __launch_bounds__(512, 4)
void gemm_tk(const unsigned short* __restrict__ A, const float* __restrict__ W0,
             const float* __restrict__ W1, void* __restrict__ C,
             int Ka, int N, int lognx, int logmx, int ldC)
{
  const int j = blockIdx.x;
  const int t = (j & 7) + 8 * (j >> (3 + lognx + logmx));
  const int nblk = (j >> 3) & ((1 << lognx) - 1);
  const int mblk = (j >> (3 + lognx)) & ((1 << logmx) - 1);
  const int n0blk = nblk * 128;
  const float* Wsel = (n0blk >= N) ? W1 : W0;
  const int n0w = (n0blk >= N) ? (n0blk - N) : n0blk;

  const int tid = threadIdx.x;
  const int lane = tid & 63;
  const int wv = tid >> 6;          // 0..7
  const int wrow = wv * (MI * 16);  // MI=2: 32 rows/wave; MI=1: 16

  __shared__ short As[2][MI * 128 * 32];  // [m][k] 64-B rows, swz32
  __shared__ short Ws[2][128 * 32];       // [n][k] 64-B rows, swz32; 2 x 8KB

  f32x4 acc[MI][8];
#pragma unroll
  for (int i = 0; i < MI; ++i)
#pragma unroll
    for (int jj = 0; jj < 8; ++jj) acc[i][jj] = f32x4{0.f, 0.f, 0.f, 0.f};

  const long ldA = 128L * Ka;
  const unsigned short* Ab = A + (long)t * Ka + (long)mblk * 128 * ldA;
  const float* Wb = Wsel + (long)t * Ka * N + n0w;

  const int n0 = (tid & 31) * 4;  // 4 consecutive n per thread (W staging)
  const int kp = tid >> 5;        // k-pair 0..15 (W staging)

  auto wload = [&](int kt, f32x4& wlo, f32x4& whi) {
    const float* Wn = Wb + (long)kt * 32 * N;
    wlo = *(const f32x4*)(Wn + (long)(kp * 2) * N + n0);
    whi = *(const f32x4*)(Wn + (long)(kp * 2 + 1) * N + n0);
  };
  auto wcvt = [&](short* buf, const f32x4& wlo, const f32x4& whi) {
#pragma unroll
    for (int jj = 0; jj < 4; ++jj) {
      int n = n0 + jj;
      *(unsigned*)((char*)buf + n * 64 + ((kp * 4) ^ swz32(n))) =
          cvt_pk_bf16(wlo[jj], whi[jj]);
    }
  };
  auto astage = [&](int kt, short* buf) {
#pragma unroll
    for (int it = 0; it < MI; ++it) {
      int ci = tid + it * 512;            // 16B chunk id; m=ci>>2
      int m = ci >> 2, cb = (ci & 3) * 16;
      gload16((const char*)(Ab + (long)kt * 32 + (long)m * ldA) + (cb ^ swz32(m)),
              (char*)buf + ci * 16);
    }
  };
  auto mfma_tile = [&](const short* abuf, const short* wbuf) {
    const int kb2 = (lane >> 4) * 16;  // k-chunk byte offset
    bf8 a[MI];
#pragma unroll
    for (int mi = 0; mi < MI; ++mi) {
      const int m0 = wrow + mi * 16 + (lane & 15);
      a[mi] = *(const bf8*)((const char*)abuf + m0 * 64 + (kb2 ^ swz32(m0)));
    }
#pragma unroll
    for (int ni = 0; ni < 8; ++ni) {
      const int n = ni * 16 + (lane & 15);
      bf8 bfr = *(const bf8*)((const char*)wbuf + n * 64 + (kb2 ^ swz32(n)));
#pragma unroll
      for (int mi = 0; mi < MI; ++mi)
        acc[mi][ni] = __builtin_amdgcn_mfma_f32_16x16x32_bf16(a[mi], bfr, acc[mi][ni], 0, 0, 0);
    }
  };

  const int nt = Ka >> 5;  // even at all call sites (8/16/64)

  f32x4 wloA, whiA, wloB, whiB;
  astage(0, &As[0][0]);
  wload(0, wloA, whiA);
  wload(1, wloB, whiB);
  wcvt(&Ws[0][0], wloA, whiA);

  for (int kt = 0; kt < nt; kt += 2) {
    __syncthreads();
    if (kt + 2 < nt) wload(kt + 2, wloA, whiA);
    if (kt + 1 < nt) astage(kt + 1, &As[1][0]);
    mfma_tile(&As[0][0], &Ws[0][0]);
    wcvt(&Ws[1][0], wloB, whiB);

    __syncthreads();
    if (kt + 3 < nt) wload(kt + 3, wloB, whiB);
    if (kt + 2 < nt) astage(kt + 2, &As[0][0]);
    mfma_tile(&As[1][0], &Ws[1][0]);
    if (kt + 2 < nt) wcvt(&Ws[0][0], wloA, whiA);
  }

  // epilogue: C/D layout col=lane&15, row=(lane>>4)*4+reg
#pragma unroll
  for (int mi = 0; mi < MI; ++mi)
#pragma unroll
    for (int ni = 0; ni < 8; ++ni)
#pragma unroll
      for (int r = 0; r < 4; ++r) {
        int m = mblk * 128 + wrow + mi * 16 + (lane >> 4) * 4 + r;
        int n = n0blk + ni * 16 + (lane & 15);
        long off = ((long)m * 128 + t) * ldC + n;
        float v = acc[mi][ni][r];
        if constexpr (OUT_BF16) reinterpret_cast<unsigned short*>(C)[off] = f2bf(v);
        else reinterpret_cast<float*>(C)[off] = v;
      }
}

// ---------------------------------------------------------------------------
// Round 16: down-proj GEMM with FUSED silu A-staging AND ln2 epilogue.
// BN=256 (full LN row per block), MI=1, mx=2 -> 256 blocks (1/CU).
// ffn stays fp32 in-register (old path round-tripped bf16 ffnb).
// Epilogue: 2 x 64-row halves; x1b restaged into dead Ws via gload16;
// per-row LN: in-lane 16-sum + shfl_xor(1,2,4,8) over the row's 16 lanes.
// ---------------------------------------------------------------------------
__global__ __launch_bounds__(512, 2)
void down_ln_k(const unsigned short* __restrict__ gu, const float* __restrict__ Wd,
               const unsigned short* __restrict__ x1, const float* __restrict__ gamma,
               const float* __restrict__ beta, float* __restrict__ out)
{
  const int j = blockIdx.x;            // 256 blocks; j%8 == t%8 (XCD grouping)
  const int t = (j & 7) + 8 * (j >> 4);
  const int mblk = (j >> 3) & 1;

  const int tid = threadIdx.x;
  const int lane = tid & 63;
  const int wv = tid >> 6;
  const int wrow = wv * 16;

  __shared__ short As[2][128 * 32];    // hid tiles, 2 x 8KB
  __shared__ short Ws[2][256 * 32];    // Wd tiles, 2 x 16KB; reused for x1 restage
  __shared__ float gsh[256], bsh[256];

  if (tid < 256) { gsh[tid] = gamma[tid]; bsh[tid] = beta[tid]; }

  f32x4 acc[16];
#pragma unroll
  for (int c = 0; c < 16; ++c) acc[c] = f32x4{0.f, 0.f, 0.f, 0.f};

  const unsigned short* gub = gu + ((long)mblk * 128 * 128 + t) * 1024;
  const float* Wb = Wd + (long)t * 512 * 256;

  const int n0 = (tid & 63) * 4;       // W staging: 4 cols
  const int kp = tid >> 6;             // W staging: k-pairs kp and kp+8

  auto wload = [&](int kt, f32x4& l0, f32x4& h0, f32x4& l1, f32x4& h1) {
    const float* Wn = Wb + (long)kt * 32 * 256;
    l0 = *(const f32x4*)(Wn + (long)(kp * 2) * 256 + n0);
    h0 = *(const f32x4*)(Wn + (long)(kp * 2 + 1) * 256 + n0);
    l1 = *(const f32x4*)(Wn + (long)((kp + 8) * 2) * 256 + n0);
    h1 = *(const f32x4*)(Wn + (long)((kp + 8) * 2 + 1) * 256 + n0);
  };
  auto wcvt = [&](short* buf, const f32x4& l0, const f32x4& h0,
                  const f32x4& l1, const f32x4& h1) {
#pragma unroll
    for (int jj = 0; jj < 4; ++jj) {
      int n = n0 + jj;
      *(unsigned*)((char*)buf + n * 64 + ((kp * 4) ^ swz32(n))) =
          cvt_pk_bf16(l0[jj], h0[jj]);
      *(unsigned*)((char*)buf + n * 64 + (((kp + 8) * 4) ^ swz32(n))) =
          cvt_pk_bf16(l1[jj], h1[jj]);
    }
  };
  auto aload_silu = [&](int kt, bf8& g8, bf8& u8) {
    const int m = tid >> 2, cb8 = (tid & 3) * 8;
    const long base = (long)m * 131072 + kt * 32 + cb8;
    g8 = *(const bf8*)(gub + base);
    u8 = *(const bf8*)(gub + base + 512);
  };
  auto awrite_silu = [&](short* buf, const bf8& g8, const bf8& u8) {
    const int m = tid >> 2, cbB = (tid & 3) * 16;
    float h[8];
#pragma unroll
    for (int jj = 0; jj < 8; ++jj) {
      float gg = bf2f((unsigned short)g8[jj]);
      float uu = bf2f((unsigned short)u8[jj]);
      h[jj] = gg / (1.f + __expf(-gg)) * uu;   // verbatim silu expression
    }
    u32x4 w;
#pragma unroll
    for (int p = 0; p < 4; ++p) w[p] = cvt_pk_bf16(h[2 * p], h[2 * p + 1]);
    *(u32x4*)((char*)buf + m * 64 + (cbB ^ swz32(m))) = w;
  };
  auto mfma_tile = [&](const short* abuf, const short* wbuf) {
    const int kb2 = (lane >> 4) * 16;
    const int m0 = wrow + (lane & 15);
    bf8 a = *(const bf8*)((const char*)abuf + m0 * 64 + (kb2 ^ swz32(m0)));
#pragma unroll
    for (int ni = 0; ni < 16; ++ni) {
      const int n = ni * 16 + (lane & 15);
      bf8 bfr = *(const bf8*)((const char*)wbuf + n * 64 + (kb2 ^ swz32(n)));
      acc[ni] = __builtin_amdgcn_mfma_f32_16x16x32_bf16(a, bfr, acc[ni], 0, 0, 0);
    }
  };

  // prologue
  {
    bf8 g0, u0;
    aload_silu(0, g0, u0);
    awrite_silu(&As[0][0], g0, u0);
    f32x4 l0, h0, l1, h1;
    wload(0, l0, h0, l1, h1);
    wcvt(&Ws[0][0], l0, h0, l1, h1);
  }
  int cur = 0;
  for (int kt = 0; kt < 16; ++kt) {
    __syncthreads();  // As[cur]/Ws[cur] ready; prior reads of other buf done
    bf8 gn, un;
    f32x4 l0, h0, l1, h1;
    const bool more = (kt + 1) < 16;
    if (more) { wload(kt + 1, l0, h0, l1, h1); aload_silu(kt + 1, gn, un); }
    mfma_tile(&As[cur][0], &Ws[cur][0]);
    if (more) {
      wcvt(&Ws[cur ^ 1][0], l0, h0, l1, h1);
      awrite_silu(&As[cur ^ 1][0], gn, un);
      cur ^= 1;
    }
  }

  // ---- fused residual + LayerNorm epilogue (two 64-row halves)
  const long mg0 = (long)mblk * 128;
  short* xsh = &Ws[0][0];  // 32KB = 64 rows x 256 bf16
  for (int hh = 0; hh < 2; ++hh) {
    __syncthreads();  // MFMA reads of Ws done / previous half's LN reads done
    // stage x1 rows [64*hh, 64*hh+64) of this m-block (coalesced 16B chunks)
#pragma unroll
    for (int it = 0; it < 4; ++it) {
      int ci = tid + it * 512;           // 0..2047; row=ci>>5, 16B col=ci&31
      int rloc = ci >> 5, c16 = ci & 31;
      gload16(x1 + ((mg0 + 64 * hh + rloc) * 128 + t) * 256 + c16 * 8,
              (char*)xsh + ci * 16);
    }
    __syncthreads();  // gload drained
    if ((wv >> 2) == hh) {               // waves owning rows in this half
#pragma unroll
      for (int r = 0; r < 4; ++r) {
        const int mloc = wrow + (lane >> 4) * 4 + r;
        const int lrow = mloc & 63;
        float x[16];
        float s = 0.f, s2 = 0.f;
#pragma unroll
        for (int ni = 0; ni < 16; ++ni) {
          int n = ni * 16 + (lane & 15);
          float v = acc[ni][r] + bf2f((unsigned short)xsh[lrow * 256 + n]);
          x[ni] = v; s += v; s2 += v * v;
        }
#pragma unroll
        for (int mm = 1; mm < 16; mm <<= 1) {
          s += __shfl_xor(s, mm, 64);
          s2 += __shfl_xor(s2, mm, 64);
        }
        float mean = s * (1.f / 256.f);
        float var = fmaxf(s2 * (1.f / 256.f) - mean * mean, 0.f);
        float inv = rsqrtf(var + 1e-5f);
#pragma unroll
        for (int ni = 0; ni < 16; ++ni) {
          int n = ni * 16 + (lane & 15);
          out[((mg0 + mloc) * 128 + t) * 256 + n] =
              (x[ni] - mean) * inv * gsh[n] + bsh[n];
        }
      }
    }
  }
}

// ---------------------------------------------------------------------------
// fp32 -> bf16 convert (X)
// ---------------------------------------------------------------------------
__global__ __launch_bounds__(256)
void cvt_bf(const float* __restrict__ in, unsigned short* __restrict__ out, long n)
{
  long i = ((long)blockIdx.x * 256 + threadIdx.x) * 8;
  if (i >= n) return;
  f32x4 a = *reinterpret_cast<const f32x4*>(in + i);
  f32x4 b = *reinterpret_cast<const f32x4*>(in + i + 4);
  u16x4 w0, w1;
#pragma unroll
  for (int j = 0; j < 4; ++j) { w0[j] = f2bf(a[j]); w1[j] = f2bf(b[j]); }
  *reinterpret_cast<u16x4*>(out + i) = w0;
  *reinterpret_cast<u16x4*>(out + i + 4) = w1;
}

// ---------------------------------------------------------------------------
// attn staging helper: write one thread's transposed V chunk into vs.
// ---------------------------------------------------------------------------
DEVI void stage_write_v(short* buf, f32x4 r0, f32x4 r1, int s2, int d0)
{
  const unsigned* a = reinterpret_cast<const unsigned*>(&r0);  // 4 words, 2 bf16 each
  const unsigned* c = reinterpret_cast<const unsigned*>(&r1);
#pragma unroll
  for (int j = 0; j < 8; ++j) {
    unsigned lo = (j & 1) ? (a[j >> 1] >> 16) : (a[j >> 1] & 0xFFFFu);
    unsigned hi = (j & 1) ? (c[j >> 1] >> 16) : (c[j >> 1] & 0xFFFFu);
    int d = d0 + j;
    *reinterpret_cast<unsigned*>(reinterpret_cast<char*>(buf) + d * 64 + ((4 * s2) ^ swz32(d))) =
        lo | (hi << 16);
  }
}

// ---------------------------------------------------------------------------
// Fused attention for one (b,h).  [= round-13/14/15 PASS verbatim]
// ---------------------------------------------------------------------------
__global__ __launch_bounds__(512, 4)
void attn_k(const unsigned short* __restrict__ qk, const unsigned short* __restrict__ vg,
            unsigned short* __restrict__ cat)
{
  const int h = blockIdx.x, b = blockIdx.y;
  const int tid = threadIdx.x, lane = tid & 63, wv = tid >> 6;
  const int wrow = wv * 16;          // 16 rows per wave

  __shared__ short ps[128 * 128];    // P [t][s] swizzled (256-B rows), 32KB
  __shared__ short vs[2][256 * 32];  // V chunk [d][s32] 64-B rows swz32, 2x16KB

  const long qkBase = ((long)b * 128) * 512 + h * 32;
  const long vgBase = ((long)b * 128) * 2048 + h * 256;  // + s*2048 + d
  const int kb_ = (lane >> 4) * 8;

  const int s2 = tid & 15;        // s = 2*s2, 2*s2+1
  const int d0 = (tid >> 4) * 8;  // 0..248

  // ---- issue chunk-0 loads (consumed after softmax, before first barrier)
  f32x4 r0, r1;
  {
    const unsigned short* src = vg + vgBase + (long)(2 * s2) * 2048 + d0;
    r0 = *reinterpret_cast<const f32x4*>(src);
    r1 = *reinterpret_cast<const f32x4*>(src + 2048);
  }

  // S = q k^T  (q/k frags straight from global; AE=32 = one MFMA K-step)
  f32x4 sacc[8];
#pragma unroll
  for (int c = 0; c < 8; ++c) sacc[c] = f32x4{0.f, 0.f, 0.f, 0.f};
  bf8 aq;
  {
    int row = wrow + (lane & 15);
    aq = *reinterpret_cast<const bf8*>(qk + qkBase + (long)row * 512 + kb_);
  }
#pragma unroll
  for (int ni = 0; ni < 8; ++ni) {
    int s = ni * 16 + (lane & 15);
    bf8 bk = *reinterpret_cast<const bf8*>(qk + qkBase + 256 + (long)s * 512 + kb_);
    sacc[ni] = __builtin_amdgcn_mfma_f32_16x16x32_bf16(aq, bk, sacc[ni], 0, 0, 0);
  }

  // wave-parallel softmax; P written unnormalized (divide after PV)
  const float scale = 0.17677669529663687f;  // 1/sqrt(32)
  float sinv[4];
#pragma unroll
  for (int r = 0; r < 4; ++r) {
    int row = wrow + (lane >> 4) * 4 + r;
    float vv[8];
    float mx = -1e30f;
#pragma unroll
    for (int c = 0; c < 8; ++c) { vv[c] = sacc[c][r] * scale; mx = fmaxf(mx, vv[c]); }
#pragma unroll
    for (int mm = 1; mm < 16; mm <<= 1) mx = fmaxf(mx, __shfl_xor(mx, mm, 64));
    float s_ = 0.f;
#pragma unroll
    for (int c = 0; c < 8; ++c) { vv[c] = __expf(vv[c] - mx); s_ += vv[c]; }
#pragma unroll
    for (int mm = 1; mm < 16; mm <<= 1) s_ += __shfl_xor(s_, mm, 64);
    sinv[r] = 1.0f / s_;
#pragma unroll
    for (int c = 0; c < 8; ++c) {
      int col = c * 16 + (lane & 15);
      int byte = row * 256 + ((col * 2) ^ swz(row));
      *reinterpret_cast<unsigned short*>(reinterpret_cast<char*>(ps) + byte) = f2bf(vv[c]);
    }
  }

  // write chunk 0 into vs[0] (loads had QK^T + softmax to land)
  stage_write_v(&vs[0][0], r0, r1, s2, d0);

  // PV over four 32-wide s-chunks, double-buffered LDS (T3 2-phase + T14).
  f32x4 oacc[16];
#pragma unroll
  for (int c = 0; c < 16; ++c) oacc[c] = f32x4{0.f, 0.f, 0.f, 0.f};

#pragma unroll 1
  for (int cs = 0; cs < 4; ++cs) {
    __syncthreads();  // vs[cs&1] published; all waves done reading vs[(cs+1)&1]
    if (cs < 3) {
      const unsigned short* src = vg + vgBase + (long)((cs + 1) * 32 + 2 * s2) * 2048 + d0;
      r0 = *reinterpret_cast<const f32x4*>(src);
      r1 = *reinterpret_cast<const f32x4*>(src + 2048);
    }
    const int kglob = cs * 32 + kb_;
    bf8 ap;
    {
      int row = wrow + (lane & 15);
      int byte = row * 256 + ((kglob * 2) ^ swz(row));
      ap = *reinterpret_cast<const bf8*>(reinterpret_cast<const char*>(ps) + byte);
    }
    __builtin_amdgcn_s_setprio(1);
#pragma unroll
    for (int c = 0; c < 16; ++c) {
      int d = c * 16 + (lane & 15);
      bf8 bv = *reinterpret_cast<const bf8*>(
          reinterpret_cast<const char*>(&vs[cs & 1][0]) + d * 64 + ((kb_ * 2) ^ swz32(d)));
      oacc[c] = __builtin_amdgcn_mfma_f32_16x16x32_bf16(ap, bv, oacc[c], 0, 0, 0);
    }
    __builtin_amdgcn_s_setprio(0);
    if (cs < 3) stage_write_v(&vs[(cs + 1) & 1][0], r0, r1, s2, d0);
  }

  // write cat[b,t,h*256+d] = out/row_sum (bf16)
#pragma unroll
  for (int c = 0; c < 16; ++c)
#pragma unroll
    for (int r = 0; r < 4; ++r) {
      int tt = wrow + (lane >> 4) * 4 + r;
      int d = c * 16 + (lane & 15);
      float v = oacc[c][r] * sinv[r];
      long off = ((long)b * 128 + tt) * 2048 + h * 256 + d;
      cat[off] = f2bf(v);
    }
}

// ---------------------------------------------------------------------------
// LayerNorm(a+b): a,b read as bf16; write fp32 (WF) and/or bf16 (WB).
// (only ln1 remains as a standalone kernel)
// ---------------------------------------------------------------------------
template<bool WF, bool WB>
__global__ __launch_bounds__(256)
void ln_k(const unsigned short* __restrict__ a, const unsigned short* __restrict__ bsrc,
          const float* __restrict__ gamma, const float* __restrict__ beta,
          float* __restrict__ of, unsigned short* __restrict__ ob)
{
  const int row = blockIdx.x * 4 + (threadIdx.x >> 6);
  const int lane = threadIdx.x & 63;
  const long base = (long)row * 256 + lane * 4;
  u16x4 ua = *reinterpret_cast<const u16x4*>(a + base);
  u16x4 ub = *reinterpret_cast<const u16x4*>(bsrc + base);
  f32x4 x;
#pragma unroll
  for (int j = 0; j < 4; ++j) x[j] = bf2f(ua[j]) + bf2f(ub[j]);
  float s = x[0] + x[1] + x[2] + x[3];
  float s2 = x[0] * x[0] + x[1] * x[1] + x[2] * x[2] + x[3] * x[3];
#pragma unroll
  for (int mm = 1; mm < 64; mm <<= 1) { s += __shfl_xor(s, mm, 64); s2 += __shfl_xor(s2, mm, 64); }
  float mean = s * (1.f / 256.f);
  float var = fmaxf(s2 * (1.f / 256.f) - mean * mean, 0.f);
  float inv = rsqrtf(var + 1e-5f);
  f32x4 g = *reinterpret_cast<const f32x4*>(gamma + lane * 4);
  f32x4 be = *reinterpret_cast<const f32x4*>(beta + lane * 4);
  f32x4 y;
#pragma unroll
  for (int j = 0; j < 4; ++j) y[j] = (x[j] - mean) * inv * g[j] + be[j];
  if constexpr (WF) *reinterpret_cast<f32x4*>(of + base) = y;
  if constexpr (WB) {
    u16x4 w;
#pragma unroll
    for (int j = 0; j < 4; ++j) w[j] = f2bf(y[j]);
    *reinterpret_cast<u16x4*>(ob + base) = w;
  }
}

// ---------------------------------------------------------------------------
// Workspace (304 MiB, lifetime reuse; ffnb + ln2 ELIMINATED this round):
//   [0,16) Xb   [16,48) qkb
//   regA @48MiB (128): vb(128, dead after attn) -> attnpb@0(16)|x1b@16(16)|
//                      gateup@32(64, read by down_ln)
//   regB @176MiB (128): cat(128, dead after O-proj)
// ---------------------------------------------------------------------------
extern "C" void kernel_launch(void* const* d_in, const int* in_sizes, int n_in,
                              void* d_out, int out_size, void* d_ws, size_t ws_size,
                              hipStream_t stream)
{
  const float* X  = (const float*)d_in[0];
  const float* Qw = (const float*)d_in[1];
  const float* Kw = (const float*)d_in[2];
  const float* Vw = (const float*)d_in[3];
  const float* Ow = (const float*)d_in[4];
  const float* Wg = (const float*)d_in[5];
  const float* Wu = (const float*)d_in[6];
  const float* Wd = (const float*)d_in[7];
  const float* g1 = (const float*)d_in[8];
  const float* b1 = (const float*)d_in[9];
  const float* g2 = (const float*)d_in[10];
  const float* b2 = (const float*)d_in[11];

  char* ws = (char*)d_ws;
  const size_t MiB = 1048576;
  unsigned short* Xb  = (unsigned short*)(ws);
  unsigned short* qkb = (unsigned short*)(ws + 16 * MiB);
  char* regA = ws + 48 * MiB;    // 128 MiB
  char* regB = regA + 128 * MiB; // 128 MiB

  unsigned short* vb     = (unsigned short*)regA;           // dead after attn_k
  unsigned short* cat    = (unsigned short*)regB;           // dead after O-proj
  unsigned short* attnpb = (unsigned short*)(regA);         // O-proj out (vb dead)
  unsigned short* x1b    = (unsigned short*)(regA + 16 * MiB);
  unsigned short* gateup = (unsigned short*)(regA + 32 * MiB);  // 64 MiB
  float* out = (float*)d_out;

  dim3 blk(256), gblk(512);
  cvt_bf<<<dim3(4096), blk, 0, stream>>>(X, Xb, (long)8388608);
  // Q|K fused: N=256 each, ldC=512, nx=4 -> 512 blocks (MI=2)
  gemm_tk<true, 2><<<dim3(512), gblk, 0, stream>>>(Xb, Qw, Kw, (void*)qkb, 256, 256, 2, 0, 512);
  // V: nx=16 -> 2048 blocks (MI=2); writes vb (b,t,2048)
  gemm_tk<true, 2><<<dim3(2048), gblk, 0, stream>>>(Xb, Vw, Vw, (void*)vb, 256, 2048, 4, 0, 2048);
  // attn reads vb directly (in-kernel transpose staging)
  attn_k<<<dim3(8, 256), gblk, 0, stream>>>(qkb, vb, cat);
  // O-proj -> bf16: MI=1 M-split (nx=2, mx=2) -> 512 blocks = 2/CU
  gemm_tk<true, 1><<<dim3(512), gblk, 0, stream>>>(cat, Ow, Ow, (void*)attnpb, 2048, 256, 1, 1, 256);
  // ln1: x1 = LN(Xb + attnpb) -> x1b only
  ln_k<false, true><<<dim3(8192), blk, 0, stream>>>(Xb, attnpb, g1, b1, (float*)nullptr, x1b);
  // gate|up fused: N=512 each, ldC=1024, nx=8 -> 1024 blocks (MI=2)
  gemm_tk<true, 2><<<dim3(1024), gblk, 0, stream>>>(x1b, Wg, Wu, (void*)gateup, 256, 512, 3, 0, 1024);
  // down-proj with fused silu staging AND fused ln2 epilogue -> fp32 d_out
  down_ln_k<<<dim3(256), gblk, 0, stream>>>(gateup, Wd, x1b, g2, b2, out);
}

// Round 17
// 443.895 us; speedup vs baseline: 1.0169x; 1.0169x over previous
//
#include <hip/hip_runtime.h>
#include <stdint.h>

// Problem constants: B=256, T=128, D=256, H=8, AE=32, DFF=512
#define DEVI static __device__ __forceinline__

typedef __attribute__((ext_vector_type(4))) float f32x4;
typedef __attribute__((ext_vector_type(8))) short bf8;     // 8 bf16 (MFMA A/B frag)
typedef __attribute__((ext_vector_type(4))) unsigned short u16x4;
typedef __attribute__((ext_vector_type(4))) unsigned int u32x4;

DEVI unsigned short f2bf(float f) {
  unsigned u = __builtin_bit_cast(unsigned, f);
  u = (u + 0x7FFFu + ((u >> 16) & 1u)) >> 16;
  return (unsigned short)u;
}
DEVI float bf2f(unsigned short s) {
  return __builtin_bit_cast(float, ((unsigned)s) << 16);
}
DEVI unsigned cvt_pk_bf16(float lo, float hi) {
  unsigned r;
  asm("v_cvt_pk_bf16_f32 %0, %1, %2" : "=v"(r) : "v"(lo), "v"(hi));
  return r;
}
// swizzle for 256-B rows (attn ps): 16B granularity, 8 slots
DEVI int swz(int row) { return (((row >> 2) ^ row) & 7) << 4; }
// swizzle for 64-B rows (gemm As/Ws, attn vs): 16B granularity, 4 slots
DEVI int swz32(int row) { return (((row >> 1) ^ row) & 3) << 4; }

DEVI void gload16(const void* g, void* l) {
  __builtin_amdgcn_global_load_lds(
      (const __attribute__((address_space(1))) unsigned*)g,
      (__attribute__((address_space(3))) unsigned*)l, 16, 0, 0);
}

// ---------------------------------------------------------------------------
// Per-t batched GEMM: C[b-rows, t, n0+*] = sum_k A * Wsel
// 2-deep W reg prefetch, x2-unrolled K-loop, named regs (round 14).
// SILU mode: A-staging computes hid = silu(gate)*up from gateup during
// staging (round 15). MI=2: BM=256; MI=1: BM=128 with mx m-blocks.
// 1-D grid, XCD same-t grouping + two-weight fusion. 8 waves, BN=128, BK=32.
// [= round-15 PASS verbatim — round-16 ln2-fusion REVERTED (1 blk/CU regression)]
// ---------------------------------------------------------------------------
template<bool OUT_BF16, int MI, bool SILU>
__global__ __launch_bounds__(512, 4)
void gemm_tk(const unsigned short* __restrict__ A, const float* __restrict__ W0,
             const float* __restrict__ W1, void* __restrict__ C,
             int Ka, int N, int lognx, int logmx, int ldC)
{
  const int j = blockIdx.x;
  const int t = (j & 7) + 8 * (j >> (3 + lognx + logmx));
  const int nblk = (j >> 3) & ((1 << lognx) - 1);
  const int mblk = (j >> (3 + lognx)) & ((1 << logmx) - 1);
  const int n0blk = nblk * 128;
  const float* Wsel = (n0blk >= N) ? W1 : W0;
  const int n0w = (n0blk >= N) ? (n0blk - N) : n0blk;

  const int tid = threadIdx.x;
  const int lane = tid & 63;
  const int wv = tid >> 6;          // 0..7
  const int wrow = wv * (MI * 16);  // MI=2: 32 rows/wave; MI=1: 16

  __shared__ short As[2][MI * 128 * 32];  // [m][k] 64-B rows, swz32
  __shared__ short Ws[2][128 * 32];       // [n][k] 64-B rows, swz32; 2 x 8KB

  f32x4 acc[MI][8];
#pragma unroll
  for (int i = 0; i < MI; ++i)
#pragma unroll
    for (int jj = 0; jj < 8; ++jj) acc[i][jj] = f32x4{0.f, 0.f, 0.f, 0.f};

  const long ldA = 128L * Ka;
  const unsigned short* Ab = A + (long)t * Ka + (long)mblk * 128 * ldA;
  const float* Wb = Wsel + (long)t * Ka * N + n0w;

  const int n0 = (tid & 31) * 4;  // 4 consecutive n per thread (W staging)
  const int kp = tid >> 5;        // k-pair 0..15 (W staging)

  // ---- helpers (compile-time buf indices at every call site)
  auto wload = [&](int kt, f32x4& wlo, f32x4& whi) {
    const float* Wn = Wb + (long)kt * 32 * N;
    wlo = *(const f32x4*)(Wn + (long)(kp * 2) * N + n0);
    whi = *(const f32x4*)(Wn + (long)(kp * 2 + 1) * N + n0);
  };
  auto wcvt = [&](short* buf, const f32x4& wlo, const f32x4& whi) {
#pragma unroll
    for (int jj = 0; jj < 4; ++jj) {
      int n = n0 + jj;
      *(unsigned*)((char*)buf + n * 64 + ((kp * 4) ^ swz32(n))) =
          cvt_pk_bf16(wlo[jj], whi[jj]);
    }
  };
  // mode 0: direct global->LDS (pre-swizzled source)
  auto astage = [&](int kt, short* buf) {
#pragma unroll
    for (int it = 0; it < MI; ++it) {
      int ci = tid + it * 512;            // 16B chunk id; m=ci>>2
      int m = ci >> 2, cb = (ci & 3) * 16;
      gload16((const char*)(Ab + (long)kt * 32 + (long)m * ldA) + (cb ^ swz32(m)),
              (char*)buf + ci * 16);
    }
  };
  // SILU mode (MI=1): A = gateup[(b*128+t)*1024 + f], gate at f, up at 512+f
  const unsigned short* gub = A + ((long)mblk * 128 * 128 + t) * 1024;
  auto aload_silu = [&](int kt, bf8& g8, bf8& u8) {
    const int m = tid >> 2, cb8 = (tid & 3) * 8;
    const long base = (long)m * 131072 + kt * 32 + cb8;
    g8 = *(const bf8*)(gub + base);
    u8 = *(const bf8*)(gub + base + 512);
  };
  auto awrite_silu = [&](short* buf, const bf8& g8, const bf8& u8) {
    const int m = tid >> 2, cbB = (tid & 3) * 16;
    float h[8];
#pragma unroll
    for (int jj = 0; jj < 8; ++jj) {
      float gg = bf2f((unsigned short)g8[jj]);
      float uu = bf2f((unsigned short)u8[jj]);
      h[jj] = gg / (1.f + __expf(-gg)) * uu;   // verbatim silu_k expression
    }
    u32x4 w;
#pragma unroll
    for (int p = 0; p < 4; ++p) w[p] = cvt_pk_bf16(h[2 * p], h[2 * p + 1]);
    *(u32x4*)((char*)buf + m * 64 + (cbB ^ swz32(m))) = w;
  };
  auto mfma_tile = [&](const short* abuf, const short* wbuf) {
    const int kb2 = (lane >> 4) * 16;  // k-chunk byte offset
    bf8 a[MI];
#pragma unroll
    for (int mi = 0; mi < MI; ++mi) {
      const int m0 = wrow + mi * 16 + (lane & 15);
      a[mi] = *(const bf8*)((const char*)abuf + m0 * 64 + (kb2 ^ swz32(m0)));
    }
#pragma unroll
    for (int ni = 0; ni < 8; ++ni) {
      const int n = ni * 16 + (lane & 15);
      bf8 bfr = *(const bf8*)((const char*)wbuf + n * 64 + (kb2 ^ swz32(n)));
#pragma unroll
      for (int mi = 0; mi < MI; ++mi)
        acc[mi][ni] = __builtin_amdgcn_mfma_f32_16x16x32_bf16(a[mi], bfr, acc[mi][ni], 0, 0, 0);
    }
  };

  const int nt = Ka >> 5;  // even at all call sites (8/16/64)

  // ---- prologue: A(0) -> As[0]; W(0) -> setA, W(1) -> setB; cvt W(0) -> Ws[0]
  f32x4 wloA, whiA, wloB, whiB;
  if constexpr (SILU) {
    bf8 g0, u0;
    aload_silu(0, g0, u0);
    awrite_silu(&As[0][0], g0, u0);
  } else {
    astage(0, &As[0][0]);
  }
  wload(0, wloA, whiA);
  wload(1, wloB, whiB);
  wcvt(&Ws[0][0], wloA, whiA);

  for (int kt = 0; kt < nt; kt += 2) {
    // ---- even phase: compute tile kt  (As[0], Ws[0])
    __syncthreads();  // A(kt)/Ws updates visible; all waves past prior reads
    bf8 gE, uE;
    if (kt + 2 < nt) wload(kt + 2, wloA, whiA);   // -> cvt at end of odd phase
    if (kt + 1 < nt) {
      if constexpr (SILU) aload_silu(kt + 1, gE, uE);
      else astage(kt + 1, &As[1][0]);
    }
    mfma_tile(&As[0][0], &Ws[0][0]);
    wcvt(&Ws[1][0], wloB, whiB);                  // W(kt+1), issued >=1 tile ago
    if constexpr (SILU) { if (kt + 1 < nt) awrite_silu(&As[1][0], gE, uE); }

    // ---- odd phase: compute tile kt+1  (As[1], Ws[1])
    __syncthreads();
    bf8 gO, uO;
    if (kt + 3 < nt) wload(kt + 3, wloB, whiB);   // -> cvt at end of next even
    if (kt + 2 < nt) {
      if constexpr (SILU) aload_silu(kt + 2, gO, uO);
      else astage(kt + 2, &As[0][0]);
    }
    mfma_tile(&As[1][0], &Ws[1][0]);
    if (kt + 2 < nt) wcvt(&Ws[0][0], wloA, whiA); // W(kt+2)
    if constexpr (SILU) { if (kt + 2 < nt) awrite_silu(&As[0][0], gO, uO); }
  }

  // epilogue: C/D layout col=lane&15, row=(lane>>4)*4+reg
#pragma unroll
  for (int mi = 0; mi < MI; ++mi)
#pragma unroll
    for (int ni = 0; ni < 8; ++ni)
#pragma unroll
      for (int r = 0; r < 4; ++r) {
        int m = mblk * 128 + wrow + mi * 16 + (lane >> 4) * 4 + r;
        int n = n0blk + ni * 16 + (lane & 15);
        long off = ((long)m * 128 + t) * ldC + n;
        float v = acc[mi][ni][r];
        if constexpr (OUT_BF16) reinterpret_cast<unsigned short*>(C)[off] = f2bf(v);
        else reinterpret_cast<float*>(C)[off] = v;
      }
}

// ---------------------------------------------------------------------------
// fp32 -> bf16 convert (X)
// ---------------------------------------------------------------------------
__global__ __launch_bounds__(256)
void cvt_bf(const float* __restrict__ in, unsigned short* __restrict__ out, long n)
{
  long i = ((long)blockIdx.x * 256 + threadIdx.x) * 8;
  if (i >= n) return;
  f32x4 a = *reinterpret_cast<const f32x4*>(in + i);
  f32x4 b = *reinterpret_cast<const f32x4*>(in + i + 4);
  u16x4 w0, w1;
#pragma unroll
  for (int j = 0; j < 4; ++j) { w0[j] = f2bf(a[j]); w1[j] = f2bf(b[j]); }
  *reinterpret_cast<u16x4*>(out + i) = w0;
  *reinterpret_cast<u16x4*>(out + i + 4) = w1;
}

// ---------------------------------------------------------------------------
// attn staging helper: write one thread's transposed V chunk into vs.
// ---------------------------------------------------------------------------
DEVI void stage_write_v(short* buf, f32x4 r0, f32x4 r1, int s2, int d0)
{
  const unsigned* a = reinterpret_cast<const unsigned*>(&r0);  // 4 words, 2 bf16 each
  const unsigned* c = reinterpret_cast<const unsigned*>(&r1);
#pragma unroll
  for (int j = 0; j < 8; ++j) {
    unsigned lo = (j & 1) ? (a[j >> 1] >> 16) : (a[j >> 1] & 0xFFFFu);
    unsigned hi = (j & 1) ? (c[j >> 1] >> 16) : (c[j >> 1] & 0xFFFFu);
    int d = d0 + j;
    *reinterpret_cast<unsigned*>(reinterpret_cast<char*>(buf) + d * 64 + ((4 * s2) ^ swz32(d))) =
        lo | (hi << 16);
  }
}

// ---------------------------------------------------------------------------
// Fused attention for one (b,h).  [= round-13/14/15 PASS verbatim]
// ---------------------------------------------------------------------------
__global__ __launch_bounds__(512, 4)
void attn_k(const unsigned short* __restrict__ qk, const unsigned short* __restrict__ vg,
            unsigned short* __restrict__ cat)
{
  const int h = blockIdx.x, b = blockIdx.y;
  const int tid = threadIdx.x, lane = tid & 63, wv = tid >> 6;
  const int wrow = wv * 16;          // 16 rows per wave

  __shared__ short ps[128 * 128];    // P [t][s] swizzled (256-B rows), 32KB
  __shared__ short vs[2][256 * 32];  // V chunk [d][s32] 64-B rows swz32, 2x16KB

  const long qkBase = ((long)b * 128) * 512 + h * 32;
  const long vgBase = ((long)b * 128) * 2048 + h * 256;  // + s*2048 + d
  const int kb_ = (lane >> 4) * 8;

  const int s2 = tid & 15;        // s = 2*s2, 2*s2+1
  const int d0 = (tid >> 4) * 8;  // 0..248

  // ---- issue chunk-0 loads (consumed after softmax, before first barrier)
  f32x4 r0, r1;
  {
    const unsigned short* src = vg + vgBase + (long)(2 * s2) * 2048 + d0;
    r0 = *reinterpret_cast<const f32x4*>(src);
    r1 = *reinterpret_cast<const f32x4*>(src + 2048);
  }

  // S = q k^T  (q/k frags straight from global; AE=32 = one MFMA K-step)
  f32x4 sacc[8];
#pragma unroll
  for (int c = 0; c < 8; ++c) sacc[c] = f32x4{0.f, 0.f, 0.f, 0.f};
  bf8 aq;
  {
    int row = wrow + (lane & 15);
    aq = *reinterpret_cast<const bf8*>(qk + qkBase + (long)row * 512 + kb_);
  }
#pragma unroll
  for (int ni = 0; ni < 8; ++ni) {
    int s = ni * 16 + (lane & 15);
    bf8 bk = *reinterpret_cast<const bf8*>(qk + qkBase + 256 + (long)s * 512 + kb_);
    sacc[ni] = __builtin_amdgcn_mfma_f32_16x16x32_bf16(aq, bk, sacc[ni], 0, 0, 0);
  }

  // wave-parallel softmax; P written unnormalized (divide after PV)
  const float scale = 0.17677669529663687f;  // 1/sqrt(32)
  float sinv[4];
#pragma unroll
  for (int r = 0; r < 4; ++r) {
    int row = wrow + (lane >> 4) * 4 + r;
    float vv[8];
    float mx = -1e30f;
#pragma unroll
    for (int c = 0; c < 8; ++c) { vv[c] = sacc[c][r] * scale; mx = fmaxf(mx, vv[c]); }
#pragma unroll
    for (int mm = 1; mm < 16; mm <<= 1) mx = fmaxf(mx, __shfl_xor(mx, mm, 64));
    float s_ = 0.f;
#pragma unroll
    for (int c = 0; c < 8; ++c) { vv[c] = __expf(vv[c] - mx); s_ += vv[c]; }
#pragma unroll
    for (int mm = 1; mm < 16; mm <<= 1) s_ += __shfl_xor(s_, mm, 64);
    sinv[r] = 1.0f / s_;
#pragma unroll
    for (int c = 0; c < 8; ++c) {
      int col = c * 16 + (lane & 15);
      int byte = row * 256 + ((col * 2) ^ swz(row));
      *reinterpret_cast<unsigned short*>(reinterpret_cast<char*>(ps) + byte) = f2bf(vv[c]);
    }
  }

  // write chunk 0 into vs[0] (loads had QK^T + softmax to land)
  stage_write_v(&vs[0][0], r0, r1, s2, d0);

  // PV over four 32-wide s-chunks, double-buffered LDS (T3 2-phase + T14).
  f32x4 oacc[16];
#pragma unroll
  for (int c = 0; c < 16; ++c) oacc[c] = f32x4{0.f, 0.f, 0.f, 0.f};

#pragma unroll 1
  for (int cs = 0; cs < 4; ++cs) {
    __syncthreads();  // vs[cs&1] published; all waves done reading vs[(cs+1)&1]
    if (cs < 3) {
      // issue next-chunk loads now; consumed after this chunk's MFMAs
      const unsigned short* src = vg + vgBase + (long)((cs + 1) * 32 + 2 * s2) * 2048 + d0;
      r0 = *reinterpret_cast<const f32x4*>(src);
      r1 = *reinterpret_cast<const f32x4*>(src + 2048);
    }
    const int kglob = cs * 32 + kb_;
    bf8 ap;
    {
      int row = wrow + (lane & 15);
      int byte = row * 256 + ((kglob * 2) ^ swz(row));
      ap = *reinterpret_cast<const bf8*>(reinterpret_cast<const char*>(ps) + byte);
    }
    __builtin_amdgcn_s_setprio(1);
#pragma unroll
    for (int c = 0; c < 16; ++c) {
      int d = c * 16 + (lane & 15);
      bf8 bv = *reinterpret_cast<const bf8*>(
          reinterpret_cast<const char*>(&vs[cs & 1][0]) + d * 64 + ((kb_ * 2) ^ swz32(d)));
      oacc[c] = __builtin_amdgcn_mfma_f32_16x16x32_bf16(ap, bv, oacc[c], 0, 0, 0);
    }
    __builtin_amdgcn_s_setprio(0);
    if (cs < 3) stage_write_v(&vs[(cs + 1) & 1][0], r0, r1, s2, d0);
  }

  // write cat[b,t,h*256+d] = out/row_sum (bf16)
#pragma unroll
  for (int c = 0; c < 16; ++c)
#pragma unroll
    for (int r = 0; r < 4; ++r) {
      int tt = wrow + (lane >> 4) * 4 + r;
      int d = c * 16 + (lane & 15);
      float v = oacc[c][r] * sinv[r];
      long off = ((long)b * 128 + tt) * 2048 + h * 256 + d;
      cat[off] = f2bf(v);
    }
}

// ---------------------------------------------------------------------------
// LayerNorm(a+b): a,b read as bf16; write fp32 (WF) and/or bf16 (WB).
// ---------------------------------------------------------------------------
template<bool WF, bool WB>
__global__ __launch_bounds__(256)
void ln_k(const unsigned short* __restrict__ a, const unsigned short* __restrict__ bsrc,
          const float* __restrict__ gamma, const float* __restrict__ beta,
          float* __restrict__ of, unsigned short* __restrict__ ob)
{
  const int row = blockIdx.x * 4 + (threadIdx.x >> 6);
  const int lane = threadIdx.x & 63;
  const long base = (long)row * 256 + lane * 4;
  u16x4 ua = *reinterpret_cast<const u16x4*>(a + base);
  u16x4 ub = *reinterpret_cast<const u16x4*>(bsrc + base);
  f32x4 x;
#pragma unroll
  for (int j = 0; j < 4; ++j) x[j] = bf2f(ua[j]) + bf2f(ub[j]);
  float s = x[0] + x[1] + x[2] + x[3];
  float s2 = x[0] * x[0] + x[1] * x[1] + x[2] * x[2] + x[3] * x[3];
#pragma unroll
  for (int mm = 1; mm < 64; mm <<= 1) { s += __shfl_xor(s, mm, 64); s2 += __shfl_xor(s2, mm, 64); }
  float mean = s * (1.f / 256.f);
  float var = fmaxf(s2 * (1.f / 256.f) - mean * mean, 0.f);
  float inv = rsqrtf(var + 1e-5f);
  f32x4 g = *reinterpret_cast<const f32x4*>(gamma + lane * 4);
  f32x4 be = *reinterpret_cast<const f32x4*>(beta + lane * 4);
  f32x4 y;
#pragma unroll
  for (int j = 0; j < 4; ++j) y[j] = (x[j] - mean) * inv * g[j] + be[j];
  if constexpr (WF) *reinterpret_cast<f32x4*>(of + base) = y;
  if constexpr (WB) {
    u16x4 w;
#pragma unroll
    for (int j = 0; j < 4; ++j) w[j] = f2bf(y[j]);
    *reinterpret_cast<u16x4*>(ob + base) = w;
  }
}

// ---------------------------------------------------------------------------
// Workspace (304 MiB, lifetime reuse):
//   [0,16) Xb   [16,48) qkb
//   regA @48MiB (128): vb(128, dead after attn) -> attnpb@0(16)|x1b@16(16)|
//                      gateup@32(64, read by down)|ffnb@96(16)
//   regB @176MiB (128): cat(128, dead after O-proj)
// ---------------------------------------------------------------------------
extern "C" void kernel_launch(void* const* d_in, const int* in_sizes, int n_in,
                              void* d_out, int out_size, void* d_ws, size_t ws_size,
                              hipStream_t stream)
{
  const float* X  = (const float*)d_in[0];
  const float* Qw = (const float*)d_in[1];
  const float* Kw = (const float*)d_in[2];
  const float* Vw = (const float*)d_in[3];
  const float* Ow = (const float*)d_in[4];
  const float* Wg = (const float*)d_in[5];
  const float* Wu = (const float*)d_in[6];
  const float* Wd = (const float*)d_in[7];
  const float* g1 = (const float*)d_in[8];
  const float* b1 = (const float*)d_in[9];
  const float* g2 = (const float*)d_in[10];
  const float* b2 = (const float*)d_in[11];

  char* ws = (char*)d_ws;
  const size_t MiB = 1048576;
  unsigned short* Xb  = (unsigned short*)(ws);
  unsigned short* qkb = (unsigned short*)(ws + 16 * MiB);
  char* regA = ws + 48 * MiB;    // 128 MiB
  char* regB = regA + 128 * MiB; // 128 MiB

  unsigned short* vb     = (unsigned short*)regA;           // dead after attn_k
  unsigned short* cat    = (unsigned short*)regB;           // dead after O-proj
  unsigned short* attnpb = (unsigned short*)(regA);         // O-proj out (vb dead)
  unsigned short* x1b    = (unsigned short*)(regA + 16 * MiB);
  unsigned short* gateup = (unsigned short*)(regA + 32 * MiB);  // 64 MiB
  unsigned short* ffnb   = (unsigned short*)(regA + 96 * MiB);  // 16 MiB
  float* out = (float*)d_out;

  dim3 blk(256), gblk(512);
  cvt_bf<<<dim3(4096), blk, 0, stream>>>(X, Xb, (long)8388608);
  // Q|K fused: N=256 each, ldC=512, nx=4 -> 512 blocks (MI=2)
  gemm_tk<true, 2, false><<<dim3(512), gblk, 0, stream>>>(Xb, Qw, Kw, (void*)qkb, 256, 256, 2, 0, 512);
  // V: nx=16 -> 2048 blocks (MI=2); writes vb (b,t,2048)
  gemm_tk<true, 2, false><<<dim3(2048), gblk, 0, stream>>>(Xb, Vw, Vw, (void*)vb, 256, 2048, 4, 0, 2048);
  // attn reads vb directly (in-kernel transpose staging)
  attn_k<<<dim3(8, 256), gblk, 0, stream>>>(qkb, vb, cat);
  // O-proj -> bf16: MI=1 M-split (nx=2, mx=2) -> 512 blocks = 2/CU
  gemm_tk<true, 1, false><<<dim3(512), gblk, 0, stream>>>(cat, Ow, Ow, (void*)attnpb, 2048, 256, 1, 1, 256);
  // ln1: x1 = LN(Xb + attnpb) -> x1b only
  ln_k<false, true><<<dim3(8192), blk, 0, stream>>>(Xb, attnpb, g1, b1, (float*)nullptr, x1b);
  // gate|up fused: N=512 each, ldC=1024, nx=8 -> 1024 blocks (MI=2)
  gemm_tk<true, 2, false><<<dim3(1024), gblk, 0, stream>>>(x1b, Wg, Wu, (void*)gateup, 256, 512, 3, 0, 1024);
  // down -> bf16 with FUSED silu A-staging (reads gateup; silu+hid eliminated)
  gemm_tk<true, 1, true><<<dim3(512), gblk, 0, stream>>>(gateup, Wd, Wd, (void*)ffnb, 512, 256, 1, 1, 256);
  // ln2: out = LN(x1b + ffnb) -> fp32 d_out
  ln_k<true, false><<<dim3(8192), blk, 0, stream>>>(x1b, ffnb, g2, b2, out, (unsigned short*)nullptr);
}